// Round 1
// baseline (910.081 us; speedup 1.0000x reference)
//
#include <hip/hip_runtime.h>
#include <hip/hip_fp16.h>
#include <stdint.h>

#define TOKENS 4096
#define IN_F   4096
#define OUT_F  11008

#define BM  128
#define BN  128
#define BK  32            // K-step in halves (64 B per row)
#define NKT (IN_F / BK)   // 128 K-tiles

typedef _Float16 half8 __attribute__((ext_vector_type(8)));
typedef float    f32x4 __attribute__((ext_vector_type(4)));

union H4 { __half2 h2[2]; uint2 u2; };
union H8 { __half2 h2[4]; uint4 u4; };

// async global->LDS, 16B per lane. LDS dest must be wave-uniform base; HW adds lane*16.
#define GLOAD16(g, l) __builtin_amdgcn_global_load_lds(                      \
    (const __attribute__((address_space(1))) uint32_t*)(g),                  \
    (__attribute__((address_space(3))) uint32_t*)(l), 16, 0, 0)

// ---------------------------------------------------------------------------
// Pre-pass 1: x fp32 -> f16.  8 elems/thread, 16.78M elems, 8192 blocks.
// ---------------------------------------------------------------------------
__global__ __launch_bounds__(256)
void convert_x_kernel(const float* __restrict__ x, __half* __restrict__ x16)
{
  const size_t i = ((size_t)blockIdx.x * 256 + threadIdx.x) * 8;
  const float4 a = *reinterpret_cast<const float4*>(x + i);
  const float4 b = *reinterpret_cast<const float4*>(x + i + 4);
  H8 r;
  r.h2[0] = __floats2half2_rn(a.x, a.y);
  r.h2[1] = __floats2half2_rn(a.z, a.w);
  r.h2[2] = __floats2half2_rn(b.x, b.y);
  r.h2[3] = __floats2half2_rn(b.z, b.w);
  *reinterpret_cast<uint4*>(x16 + i) = r.u4;
}

// ---------------------------------------------------------------------------
// Pre-pass 2: packed int4 (one byte per int32) -> f16 weights, row-major
// [OUT_F][IN_F]. 4 int32 -> 8 weights per thread. 22016 blocks.
// Dequant in fp32 (w = nib*s - z*s), round once to f16.
// ---------------------------------------------------------------------------
__global__ __launch_bounds__(256)
void dequant_w_kernel(const int* __restrict__ wq,
                      const float* __restrict__ scale,
                      const float* __restrict__ zero,
                      __half* __restrict__ w16)
{
  const size_t i = ((size_t)blockIdx.x * 256 + threadIdx.x) * 4; // int32 index
  const int row = (int)(i >> 11);                                // IN_F/2 = 2048 int32 per row
  const float s  = scale[row];
  const float nb = -zero[row] * s;
  const int4 v = *reinterpret_cast<const int4*>(wq + i);
  H8 r;
  r.h2[0] = __floats2half2_rn(fmaf((float)(v.x & 15), s, nb),
                              fmaf((float)((v.x >> 4) & 15), s, nb));
  r.h2[1] = __floats2half2_rn(fmaf((float)(v.y & 15), s, nb),
                              fmaf((float)((v.y >> 4) & 15), s, nb));
  r.h2[2] = __floats2half2_rn(fmaf((float)(v.z & 15), s, nb),
                              fmaf((float)((v.z >> 4) & 15), s, nb));
  r.h2[3] = __floats2half2_rn(fmaf((float)(v.w & 15), s, nb),
                              fmaf((float)((v.w >> 4) & 15), s, nb));
  *reinterpret_cast<uint4*>(w16 + i * 2) = r.u4;
}

// ---------------------------------------------------------------------------
// Main GEMM: C[M][N] = A[M][K] * B[N][K]^T, all f16 in, fp32 out.
// m97 structure: 128x128 tile, BK=32, 4 waves, global_load_lds dwordx4
// staging into linear LDS, 2 barriers per K-step, 16x16x32 MFMA.
// ---------------------------------------------------------------------------
__global__ __launch_bounds__(256, 2)
void gemm_f16_kernel(const __half* __restrict__ A,
                     const __half* __restrict__ B,
                     float* __restrict__ out)
{
  __shared__ __half As[BM * BK];   // 8 KB, linear (global_load_lds needs no pad)
  __shared__ __half Bs[BN * BK];   // 8 KB

  const int tid  = threadIdx.x;
  const int n0   = blockIdx.x * BN;   // 86 n-tiles
  const int m0   = blockIdx.y * BM;   // 32 m-tiles
  const int lane = tid & 63;
  const int wave = tid >> 6;          // 0..3
  const int wm   = (wave >> 1) * 64;
  const int wn   = (wave & 1) * 64;

  // Staging: tile = 512 x 16B chunks; chunk c: row = c>>2, sub = c&3.
  // Insn 0 covers chunks [0,256) (c = tid), insn 1 covers [256,512).
  const int rowc = tid >> 2;          // 0..63
  const int subc = tid & 3;
  const __half* aSrc0 = A + (size_t)(m0 + rowc) * IN_F + subc * 8;
  const __half* aSrc1 = A + (size_t)(m0 + 64 + rowc) * IN_F + subc * 8;
  const __half* bSrc0 = B + (size_t)(n0 + rowc) * IN_F + subc * 8;
  const __half* bSrc1 = B + (size_t)(n0 + 64 + rowc) * IN_F + subc * 8;
  // wave-uniform LDS bases (chunk base * 8 halves)
  __half* aDst0 = &As[(wave * 64) * 8];
  __half* aDst1 = &As[(256 + wave * 64) * 8];
  __half* bDst0 = &Bs[(wave * 64) * 8];
  __half* bDst1 = &Bs[(256 + wave * 64) * 8];

  f32x4 acc[4][4];
#pragma unroll
  for (int i = 0; i < 4; ++i)
#pragma unroll
    for (int j = 0; j < 4; ++j)
      acc[i][j] = (f32x4){0.f, 0.f, 0.f, 0.f};

  const int fm = lane & 15;
  const int q4 = lane >> 4;

  for (int kt = 0; kt < NKT; ++kt) {
    const size_t ko = (size_t)kt * BK;
    GLOAD16(aSrc0 + ko, aDst0);
    GLOAD16(aSrc1 + ko, aDst1);
    GLOAD16(bSrc0 + ko, bDst0);
    GLOAD16(bSrc1 + ko, bDst1);
    __syncthreads();   // compiler emits vmcnt(0) drain before s_barrier

    half8 af[4], bf[4];
#pragma unroll
    for (int i = 0; i < 4; ++i)
      af[i] = *reinterpret_cast<const half8*>(&As[(wm + i * 16 + fm) * BK + q4 * 8]);
#pragma unroll
    for (int j = 0; j < 4; ++j)
      bf[j] = *reinterpret_cast<const half8*>(&Bs[(wn + j * 16 + fm) * BK + q4 * 8]);
#pragma unroll
    for (int i = 0; i < 4; ++i)
#pragma unroll
      for (int j = 0; j < 4; ++j)
        acc[i][j] = __builtin_amdgcn_mfma_f32_16x16x32_f16(af[i], bf[j], acc[i][j], 0, 0, 0);
    __syncthreads();   // protect LDS from next iteration's staging
  }

  // epilogue: C/D layout col=lane&15 (n), row=(lane>>4)*4+reg (m)
  const int col = lane & 15;
  const int r0q = (lane >> 4) * 4;
#pragma unroll
  for (int i = 0; i < 4; ++i) {
#pragma unroll
    for (int j = 0; j < 4; ++j) {
#pragma unroll
      for (int r = 0; r < 4; ++r) {
        const int m = m0 + wm + i * 16 + r0q + r;
        const int n = n0 + wn + j * 16 + col;
        out[(size_t)m * OUT_F + n] = acc[i][j][r];
      }
    }
  }
}

// ---------------------------------------------------------------------------
// Fallback (previous verified kernel) — used only if workspace is too small.
// ---------------------------------------------------------------------------
#define LDT 40

__device__ inline __half2 dequant_byte(int v, __half2 s2, __half2 b2) {
  float lo = (float)(v & 15);
  float hi = (float)((v >> 4) & 15);
  return __hfma2(__floats2half2_rn(lo, hi), s2, b2);
}

__global__ __launch_bounds__(256, 2)
void int4_gemm_kernel(const float* __restrict__ x,
                      const int* __restrict__ wq,
                      const float* __restrict__ scale,
                      const float* __restrict__ zero,
                      float* __restrict__ out)
{
  __shared__ __half As[BM * LDT];
  __shared__ __half Bs[BN * LDT];

  const int tid  = threadIdx.x;
  const int n0   = blockIdx.x * BN;
  const int m0   = blockIdx.y * BM;
  const int lane = tid & 63;
  const int wave = tid >> 6;
  const int wm   = (wave >> 1) * 64;
  const int wn   = (wave & 1) * 64;

  const int rowb  = tid >> 1;
  const int bhalf = tid & 1;
  const float s = scale[n0 + rowb];
  const float z = zero[n0 + rowb];
  const __half2 s2 = __floats2half2_rn(s, s);
  const float   nb = -z * s;
  const __half2 b2 = __floats2half2_rn(nb, nb);
  const int* wp = wq + (size_t)(n0 + rowb) * (IN_F / 2) + bhalf * 8;

  const float* xp[4];
  int arow[4], ac4[4];
#pragma unroll
  for (int i = 0; i < 4; ++i) {
    int idx = tid + i * 256;
    arow[i] = idx >> 3;
    ac4[i]  = idx & 7;
    xp[i] = x + (size_t)(m0 + arow[i]) * IN_F + ac4[i] * 4;
  }

  f32x4 acc[4][4];
#pragma unroll
  for (int i = 0; i < 4; ++i)
#pragma unroll
    for (int j = 0; j < 4; ++j)
      acc[i][j] = (f32x4){0.f, 0.f, 0.f, 0.f};

  float4 apf[4];
  int4   bpf0, bpf1;
#pragma unroll
  for (int i = 0; i < 4; ++i) apf[i] = *(const float4*)(xp[i]);
  bpf0 = *(const int4*)(wp);
  bpf1 = *(const int4*)(wp + 4);

  for (int kt = 0; kt < NKT; ++kt) {
#pragma unroll
    for (int i = 0; i < 4; ++i) {
      H4 t;
      t.h2[0] = __floats2half2_rn(apf[i].x, apf[i].y);
      t.h2[1] = __floats2half2_rn(apf[i].z, apf[i].w);
      *reinterpret_cast<uint2*>(&As[arow[i] * LDT + ac4[i] * 4]) = t.u2;
    }
    {
      H8 r0, r1;
      r0.h2[0] = dequant_byte(bpf0.x, s2, b2);
      r0.h2[1] = dequant_byte(bpf0.y, s2, b2);
      r0.h2[2] = dequant_byte(bpf0.z, s2, b2);
      r0.h2[3] = dequant_byte(bpf0.w, s2, b2);
      r1.h2[0] = dequant_byte(bpf1.x, s2, b2);
      r1.h2[1] = dequant_byte(bpf1.y, s2, b2);
      r1.h2[2] = dequant_byte(bpf1.z, s2, b2);
      r1.h2[3] = dequant_byte(bpf1.w, s2, b2);
      *reinterpret_cast<uint4*>(&Bs[rowb * LDT + bhalf * 16 + 0]) = r0.u4;
      *reinterpret_cast<uint4*>(&Bs[rowb * LDT + bhalf * 16 + 8]) = r1.u4;
    }
    if (kt + 1 < NKT) {
#pragma unroll
      for (int i = 0; i < 4; ++i) apf[i] = *(const float4*)(xp[i] + (kt + 1) * BK);
      bpf0 = *(const int4*)(wp + (size_t)(kt + 1) * 16);
      bpf1 = *(const int4*)(wp + (size_t)(kt + 1) * 16 + 4);
    }
    __syncthreads();

    const int fm = lane & 15;
    const int q4 = lane >> 4;
    half8 af[4], bf[4];
#pragma unroll
    for (int i = 0; i < 4; ++i)
      af[i] = *reinterpret_cast<const half8*>(&As[(wm + i * 16 + fm) * LDT + q4 * 8]);
#pragma unroll
    for (int j = 0; j < 4; ++j)
      bf[j] = *reinterpret_cast<const half8*>(&Bs[(wn + j * 16 + fm) * LDT + q4 * 8]);
#pragma unroll
    for (int i = 0; i < 4; ++i)
#pragma unroll
      for (int j = 0; j < 4; ++j)
        acc[i][j] = __builtin_amdgcn_mfma_f32_16x16x32_f16(af[i], bf[j], acc[i][j], 0, 0, 0);
    __syncthreads();
  }

  const int col = lane & 15;
  const int r0q = (lane >> 4) * 4;
#pragma unroll
  for (int i = 0; i < 4; ++i) {
#pragma unroll
    for (int j = 0; j < 4; ++j) {
#pragma unroll
      for (int r = 0; r < 4; ++r) {
        const int m = m0 + wm + i * 16 + r0q + r;
        const int n = n0 + wn + j * 16 + col;
        out[(size_t)m * OUT_F + n] = acc[i][j][r];
      }
    }
  }
}

// ---------------------------------------------------------------------------
extern "C" void kernel_launch(void* const* d_in, const int* in_sizes, int n_in,
                              void* d_out, int out_size, void* d_ws, size_t ws_size,
                              hipStream_t stream) {
  const float* x     = (const float*)d_in[0];
  const int*   wq    = (const int*)d_in[1];     // integer inputs arrive as int32
  const float* scale = (const float*)d_in[2];
  const float* zero  = (const float*)d_in[3];
  float* out = (float*)d_out;

  const size_t X16_BYTES = (size_t)TOKENS * IN_F * sizeof(__half);   // 33.55 MB
  const size_t W16_BYTES = (size_t)OUT_F * IN_F * sizeof(__half);    // 90.18 MB

  dim3 grid(OUT_F / BN, TOKENS / BM);   // 86 x 32 = 2752 blocks

  if (ws_size >= X16_BYTES + W16_BYTES) {
    __half* x16 = (__half*)d_ws;
    __half* w16 = (__half*)((char*)d_ws + X16_BYTES);
    convert_x_kernel<<<(TOKENS * IN_F / 8) / 256, 256, 0, stream>>>(x, x16);
    dequant_w_kernel<<<(OUT_F * (IN_F / 2) / 4) / 256, 256, 0, stream>>>(wq, scale, zero, w16);
    gemm_f16_kernel<<<grid, 256, 0, stream>>>(x16, w16, out);
  } else {
    int4_gemm_kernel<<<grid, 256, 0, stream>>>(x, wq, scale, zero, out);
  }
}

// Round 2
// 619.373 us; speedup vs baseline: 1.4694x; 1.4694x over previous
//
#include <hip/hip_runtime.h>
#include <hip/hip_fp16.h>
#include <stdint.h>

#define TOKENS 4096
#define IN_F   4096
#define OUT_F  11008

typedef _Float16 half8 __attribute__((ext_vector_type(8)));
typedef float    f32x4 __attribute__((ext_vector_type(4)));

union H4 { __half2 h2[2]; uint2 u2; };
union H8 { __half2 h2[4]; uint4 u4; };

// async global->LDS, 16B per lane. LDS dest is wave-uniform base; HW adds lane*16.
#define GLOAD16(g, l) __builtin_amdgcn_global_load_lds(                      \
    (const __attribute__((address_space(1))) uint32_t*)(g),                  \
    (__attribute__((address_space(3))) uint32_t*)(l), 16, 0, 0)

// ---------------------------------------------------------------------------
// Pre-pass 1: x fp32 -> f16.
// ---------------------------------------------------------------------------
__global__ __launch_bounds__(256)
void convert_x_kernel(const float* __restrict__ x, __half* __restrict__ x16)
{
  const size_t i = ((size_t)blockIdx.x * 256 + threadIdx.x) * 8;
  const float4 a = *reinterpret_cast<const float4*>(x + i);
  const float4 b = *reinterpret_cast<const float4*>(x + i + 4);
  H8 r;
  r.h2[0] = __floats2half2_rn(a.x, a.y);
  r.h2[1] = __floats2half2_rn(a.z, a.w);
  r.h2[2] = __floats2half2_rn(b.x, b.y);
  r.h2[3] = __floats2half2_rn(b.z, b.w);
  *reinterpret_cast<uint4*>(x16 + i) = r.u4;
}

// ---------------------------------------------------------------------------
// Pre-pass 2: packed int4 (one byte per int32) -> f16 weights [OUT_F][IN_F].
// ---------------------------------------------------------------------------
__global__ __launch_bounds__(256)
void dequant_w_kernel(const int* __restrict__ wq,
                      const float* __restrict__ scale,
                      const float* __restrict__ zero,
                      __half* __restrict__ w16)
{
  const size_t i = ((size_t)blockIdx.x * 256 + threadIdx.x) * 4; // int32 index
  const int row = (int)(i >> 11);                                // 2048 int32 per row
  const float s  = scale[row];
  const float nb = -zero[row] * s;
  const int4 v = *reinterpret_cast<const int4*>(wq + i);
  H8 r;
  r.h2[0] = __floats2half2_rn(fmaf((float)(v.x & 15), s, nb),
                              fmaf((float)((v.x >> 4) & 15), s, nb));
  r.h2[1] = __floats2half2_rn(fmaf((float)(v.y & 15), s, nb),
                              fmaf((float)((v.y >> 4) & 15), s, nb));
  r.h2[2] = __floats2half2_rn(fmaf((float)(v.z & 15), s, nb),
                              fmaf((float)((v.z >> 4) & 15), s, nb));
  r.h2[3] = __floats2half2_rn(fmaf((float)(v.w & 15), s, nb),
                              fmaf((float)((v.w >> 4) & 15), s, nb));
  *reinterpret_cast<uint4*>(w16 + i * 2) = r.u4;
}

// ---------------------------------------------------------------------------
// Main GEMM: 256x256 tile, BK=64, 8 waves (2Mx4N), 8-phase schedule with
// counted vmcnt(4), XOR-swizzled LDS (both-sides via pre-swizzled gload src),
// setprio around MFMA clusters, bijective XCD blockIdx swizzle.
//
// LDS map (halves): buf b at b*32768. A0=+0, A1=+8192, B0=+16384, B1=+24576.
// Half-tile = 128 rows x 64 halves (16KB). LDS row rh <-> global row grow0+rh.
// Swizzle: within a 128B row, 16B slot s holds global slot s ^ (row&7).
//
// Pipeline per iteration (K-tiles e=2i in buf0, o=2i+1 in buf1), 8 phases:
//  ph0 e: read all B(e)+A m01(e); stage o.A0 -> buf1.A0
//  ph1 e: read A m23(e);          stage o.A1 -> buf1.A1
//  ph2 e: read A m45(e);          stage (e+2).B0 -> buf0.B0  (old consumed ph0)
//  ph3 e: read A m67(e);          stage (e+2).B1 -> buf0.B1 ; vmcnt(4)
//  ph4 o: read all B(o)+A m01(o); stage (e+2).A0 -> buf0.A0  (old consumed ph3)
//  ph5 o: read A m23(o);          stage (e+2).A1 -> buf0.A1
//  ph6 o: read A m45(o);          stage (o+2).B0 -> buf1.B0  (old consumed ph4)
//  ph7 o: read A m67(o);          stage (o+2).B1 -> buf1.B1 ; vmcnt(4)
// vmcnt(4) = 2 loads/phase x last 2 phases allowed outstanding.
// ---------------------------------------------------------------------------

#define VMW4 asm volatile("s_waitcnt vmcnt(4)" ::: "memory")

#define STAGE_A(H, K0, LB)                                                    \
  do {                                                                        \
    GLOAD16(apst + (H) * 128 * IN_F + (K0), &smem[(LB) + c0 * 512]);          \
    GLOAD16(apst + (H) * 128 * IN_F + 8 * IN_F + (K0),                        \
            &smem[(LB) + c0 * 512 + 512]);                                    \
  } while (0)

#define STAGE_B(H, K0, LB)                                                    \
  do {                                                                        \
    GLOAD16(bpst + (H) * 128 * IN_F + (K0), &smem[(LB) + c0 * 512]);          \
    GLOAD16(bpst + (H) * 128 * IN_F + 8 * IN_F + (K0),                        \
            &smem[(LB) + c0 * 512 + 512]);                                    \
  } while (0)

#define PHASE(BUF, MB, READB, STAGE_STMT, DOWAIT)                             \
  do {                                                                        \
    const int _ar = arootA + (BUF) * 32768;                                   \
    const int _br = brootB + (BUF) * 32768;                                   \
    if (READB) {                                                              \
      _Pragma("unroll")                                                       \
      for (int _j = 0; _j < 4; ++_j) {                                        \
        const int _rh = bn_rh + _j * 16;                                      \
        bfr[_j][0] = *(const half8*)&smem[_br + _rh * 64 + acol0];            \
        bfr[_j][1] = *(const half8*)&smem[_br + _rh * 64 + acol1];            \
      }                                                                       \
    }                                                                         \
    half8 _af[2][2];                                                          \
    _Pragma("unroll")                                                         \
    for (int _ii = 0; _ii < 2; ++_ii) {                                       \
      const int _rh = am_rh + ((MB) * 2 + _ii) * 16;                          \
      _af[_ii][0] = *(const half8*)&smem[_ar + _rh * 64 + acol0];             \
      _af[_ii][1] = *(const half8*)&smem[_ar + _rh * 64 + acol1];             \
    }                                                                         \
    STAGE_STMT;                                                               \
    __builtin_amdgcn_sched_barrier(0);                                        \
    __builtin_amdgcn_s_barrier();                                             \
    asm volatile("s_waitcnt lgkmcnt(0)" ::: "memory");                        \
    __builtin_amdgcn_sched_barrier(0);                                        \
    __builtin_amdgcn_s_setprio(1);                                            \
    _Pragma("unroll")                                                         \
    for (int _ii = 0; _ii < 2; ++_ii)                                         \
      _Pragma("unroll")                                                       \
      for (int _j = 0; _j < 4; ++_j) {                                        \
        acc[(MB) * 2 + _ii][_j] = __builtin_amdgcn_mfma_f32_16x16x32_f16(     \
            _af[_ii][0], bfr[_j][0], acc[(MB) * 2 + _ii][_j], 0, 0, 0);       \
        acc[(MB) * 2 + _ii][_j] = __builtin_amdgcn_mfma_f32_16x16x32_f16(     \
            _af[_ii][1], bfr[_j][1], acc[(MB) * 2 + _ii][_j], 0, 0, 0);       \
      }                                                                       \
    __builtin_amdgcn_s_setprio(0);                                            \
    if (DOWAIT) { VMW4; }                                                     \
    __builtin_amdgcn_sched_barrier(0);                                        \
    __builtin_amdgcn_s_barrier();                                             \
  } while (0)

__global__ __launch_bounds__(512, 2)
void gemm256_kernel(const __half* __restrict__ A16,
                    const __half* __restrict__ W16,
                    float* __restrict__ out)
{
  __shared__ __half smem[65536];   // 128 KB: 2 bufs x (A 32KB + B 32KB)

  // bijective XCD swizzle: 688 = 8 * 86
  const int bid = blockIdx.x;
  const int wg  = (bid & 7) * 86 + (bid >> 3);
  const int mt  = wg / 43;
  const int nt  = wg - mt * 43;
  const int m0  = mt * 256;
  const int n0  = nt * 256;

  const int tid  = threadIdx.x;
  const int lane = tid & 63;
  const int wave = tid >> 6;          // 0..7
  const int wr   = wave >> 2;         // 0..1  (M)
  const int wc   = wave & 3;          // 0..3  (N)
  const int fm   = lane & 15;
  const int q4   = lane >> 4;

  // fragment-read constants (swizzled column offsets, halves)
  const int swz   = (fm & 7) << 3;
  const int acol0 = (q4 * 8) ^ swz;          // ks=0
  const int acol1 = (32 + q4 * 8) ^ swz;     // ks=1
  const int arootA = wr * 8192;              // + buf*32768
  const int brootB = 16384 + (wc >> 1) * 8192;
  const int am_rh  = fm;                     // + mfrag*16
  const int bn_rh  = (wc & 1) * 64 + fm;     // + nfrag*16

  // staging constants: chunk c covers half-tile rows [c*8, c*8+8)
  const int c0 = wave * 2;
  const int sr = lane >> 3;                         // sub-row 0..7 (= row&7)
  const int sc = ((lane & 7) ^ sr) * 8;             // pre-swizzled source slot
  const __half* apst = A16 + (size_t)(m0 + c0 * 8 + sr) * IN_F + sc;
  const __half* bpst = W16 + (size_t)(n0 + c0 * 8 + sr) * IN_F + sc;

  f32x4 acc[8][4];
#pragma unroll
  for (int i = 0; i < 8; ++i)
#pragma unroll
    for (int j = 0; j < 4; ++j)
      acc[i][j] = (f32x4){0.f, 0.f, 0.f, 0.f};

  half8 bfr[4][2];

  // ---- prologue: K0.B, K0.A -> buf0; K1.B -> buf1.B (K1.A staged in ph0/ph1)
  STAGE_B(0, 0, 16384);
  STAGE_B(1, 0, 16384 + 8192);
  STAGE_A(0, 0, 0);
  STAGE_A(1, 0, 8192);
  STAGE_B(0, 64, 32768 + 16384);
  STAGE_B(1, 64, 32768 + 16384 + 8192);
  VMW4;                               // K0 fully landed; K1.B may be in flight
  __builtin_amdgcn_sched_barrier(0);
  __builtin_amdgcn_s_barrier();

#pragma unroll 1
  for (int it = 0; it < 32; ++it) {
    const int k_o = (it * 2 + 1) * 64;
    const int ke2 = ((it * 2 + 2) & 63) * 64;   // wrap keeps tail in-bounds
    const int ko2 = ((it * 2 + 3) & 63) * 64;
    // K-tile e from buf0
    PHASE(0, 0, 1, STAGE_A(0, k_o, 32768 + 0),            0);
    PHASE(0, 1, 0, STAGE_A(1, k_o, 32768 + 8192),         0);
    PHASE(0, 2, 0, STAGE_B(0, ke2, 16384),                0);
    PHASE(0, 3, 0, STAGE_B(1, ke2, 16384 + 8192),         1);
    // K-tile o from buf1
    PHASE(1, 0, 1, STAGE_A(0, ke2, 0),                    0);
    PHASE(1, 1, 0, STAGE_A(1, ke2, 8192),                 0);
    PHASE(1, 2, 0, STAGE_B(0, ko2, 32768 + 16384),        0);
    PHASE(1, 3, 0, STAGE_B(1, ko2, 32768 + 16384 + 8192), 1);
  }

  asm volatile("s_waitcnt vmcnt(0)" ::: "memory");  // drain tail stages

  // ---- epilogue: C/D layout col=lane&15 (n), row=(lane>>4)*4+reg (m)
  const int mbase = m0 + wr * 128 + q4 * 4;
  const int nbase = n0 + wc * 64 + fm;
#pragma unroll
  for (int i = 0; i < 8; ++i) {
#pragma unroll
    for (int j = 0; j < 4; ++j) {
#pragma unroll
      for (int r = 0; r < 4; ++r) {
        out[(size_t)(mbase + i * 16 + r) * OUT_F + (nbase + j * 16)] = acc[i][j][r];
      }
    }
  }
}

// ---------------------------------------------------------------------------
// Fallback (previous verified fused kernel) — used only if workspace too small.
// ---------------------------------------------------------------------------
#define BM  128
#define BN  128
#define BK  32
#define LDT 40
#define NKT (IN_F / BK)

__device__ inline __half2 dequant_byte(int v, __half2 s2, __half2 b2) {
  float lo = (float)(v & 15);
  float hi = (float)((v >> 4) & 15);
  return __hfma2(__floats2half2_rn(lo, hi), s2, b2);
}

__global__ __launch_bounds__(256, 2)
void int4_gemm_kernel(const float* __restrict__ x,
                      const int* __restrict__ wq,
                      const float* __restrict__ scale,
                      const float* __restrict__ zero,
                      float* __restrict__ out)
{
  __shared__ __half As[BM * LDT];
  __shared__ __half Bs[BN * LDT];

  const int tid  = threadIdx.x;
  const int n0   = blockIdx.x * BN;
  const int m0   = blockIdx.y * BM;
  const int lane = tid & 63;
  const int wave = tid >> 6;
  const int wm   = (wave >> 1) * 64;
  const int wn   = (wave & 1) * 64;

  const int rowb  = tid >> 1;
  const int bhalf = tid & 1;
  const float s = scale[n0 + rowb];
  const float z = zero[n0 + rowb];
  const __half2 s2 = __floats2half2_rn(s, s);
  const float   nb = -z * s;
  const __half2 b2 = __floats2half2_rn(nb, nb);
  const int* wp = wq + (size_t)(n0 + rowb) * (IN_F / 2) + bhalf * 8;

  const float* xp[4];
  int arow[4], ac4[4];
#pragma unroll
  for (int i = 0; i < 4; ++i) {
    int idx = tid + i * 256;
    arow[i] = idx >> 3;
    ac4[i]  = idx & 7;
    xp[i] = x + (size_t)(m0 + arow[i]) * IN_F + ac4[i] * 4;
  }

  f32x4 acc[4][4];
#pragma unroll
  for (int i = 0; i < 4; ++i)
#pragma unroll
    for (int j = 0; j < 4; ++j)
      acc[i][j] = (f32x4){0.f, 0.f, 0.f, 0.f};

  float4 apf[4];
  int4   bpf0, bpf1;
#pragma unroll
  for (int i = 0; i < 4; ++i) apf[i] = *(const float4*)(xp[i]);
  bpf0 = *(const int4*)(wp);
  bpf1 = *(const int4*)(wp + 4);

  for (int kt = 0; kt < NKT; ++kt) {
#pragma unroll
    for (int i = 0; i < 4; ++i) {
      H4 t;
      t.h2[0] = __floats2half2_rn(apf[i].x, apf[i].y);
      t.h2[1] = __floats2half2_rn(apf[i].z, apf[i].w);
      *reinterpret_cast<uint2*>(&As[arow[i] * LDT + ac4[i] * 4]) = t.u2;
    }
    {
      H8 r0, r1;
      r0.h2[0] = dequant_byte(bpf0.x, s2, b2);
      r0.h2[1] = dequant_byte(bpf0.y, s2, b2);
      r0.h2[2] = dequant_byte(bpf0.z, s2, b2);
      r0.h2[3] = dequant_byte(bpf0.w, s2, b2);
      r1.h2[0] = dequant_byte(bpf1.x, s2, b2);
      r1.h2[1] = dequant_byte(bpf1.y, s2, b2);
      r1.h2[2] = dequant_byte(bpf1.z, s2, b2);
      r1.h2[3] = dequant_byte(bpf1.w, s2, b2);
      *reinterpret_cast<uint4*>(&Bs[rowb * LDT + bhalf * 16 + 0]) = r0.u4;
      *reinterpret_cast<uint4*>(&Bs[rowb * LDT + bhalf * 16 + 8]) = r1.u4;
    }
    if (kt + 1 < NKT) {
#pragma unroll
      for (int i = 0; i < 4; ++i) apf[i] = *(const float4*)(xp[i] + (kt + 1) * BK);
      bpf0 = *(const int4*)(wp + (size_t)(kt + 1) * 16);
      bpf1 = *(const int4*)(wp + (size_t)(kt + 1) * 16 + 4);
    }
    __syncthreads();

    const int fm = lane & 15;
    const int q4 = lane >> 4;
    half8 af[4], bf[4];
#pragma unroll
    for (int i = 0; i < 4; ++i)
      af[i] = *reinterpret_cast<const half8*>(&As[(wm + i * 16 + fm) * LDT + q4 * 8]);
#pragma unroll
    for (int j = 0; j < 4; ++j)
      bf[j] = *reinterpret_cast<const half8*>(&Bs[(wn + j * 16 + fm) * LDT + q4 * 8]);
#pragma unroll
    for (int i = 0; i < 4; ++i)
#pragma unroll
      for (int j = 0; j < 4; ++j)
        acc[i][j] = __builtin_amdgcn_mfma_f32_16x16x32_f16(af[i], bf[j], acc[i][j], 0, 0, 0);
    __syncthreads();
  }

  const int col = lane & 15;
  const int r0q = (lane >> 4) * 4;
#pragma unroll
  for (int i = 0; i < 4; ++i) {
#pragma unroll
    for (int j = 0; j < 4; ++j) {
#pragma unroll
      for (int r = 0; r < 4; ++r) {
        const int m = m0 + wm + i * 16 + r0q + r;
        const int n = n0 + wn + j * 16 + col;
        out[(size_t)m * OUT_F + n] = acc[i][j][r];
      }
    }
  }
}

// ---------------------------------------------------------------------------
extern "C" void kernel_launch(void* const* d_in, const int* in_sizes, int n_in,
                              void* d_out, int out_size, void* d_ws, size_t ws_size,
                              hipStream_t stream) {
  const float* x     = (const float*)d_in[0];
  const int*   wq    = (const int*)d_in[1];
  const float* scale = (const float*)d_in[2];
  const float* zero  = (const float*)d_in[3];
  float* out = (float*)d_out;

  const size_t X16_BYTES = (size_t)TOKENS * IN_F * sizeof(__half);
  const size_t W16_BYTES = (size_t)OUT_F * IN_F * sizeof(__half);

  if (ws_size >= X16_BYTES + W16_BYTES) {
    __half* x16 = (__half*)d_ws;
    __half* w16 = (__half*)((char*)d_ws + X16_BYTES);
    convert_x_kernel<<<(TOKENS * IN_F / 8) / 256, 256, 0, stream>>>(x, x16);
    dequant_w_kernel<<<(OUT_F * (IN_F / 2) / 4) / 256, 256, 0, stream>>>(wq, scale, zero, w16);
    gemm256_kernel<<<dim3((OUT_F / 256) * (TOKENS / 256)), 512, 0, stream>>>(x16, w16, out);
  } else {
    dim3 grid(OUT_F / BN, TOKENS / BM);
    int4_gemm_kernel<<<grid, 256, 0, stream>>>(x, wq, scale, zero, out);
  }
}

// Round 3
// 607.867 us; speedup vs baseline: 1.4972x; 1.0189x over previous
//
#include <hip/hip_runtime.h>
#include <hip/hip_fp16.h>
#include <stdint.h>

#define TOKENS 4096
#define IN_F   4096
#define OUT_F  11008

typedef _Float16 half8 __attribute__((ext_vector_type(8)));
typedef float    f32x4 __attribute__((ext_vector_type(4)));

union H4 { __half2 h2[2]; uint2 u2; };
union H8 { __half2 h2[4]; uint4 u4; };

// async global->LDS, 16B per lane. LDS dest is wave-uniform base; HW adds lane*16.
#define GLOAD16(g, l) __builtin_amdgcn_global_load_lds(                      \
    (const __attribute__((address_space(1))) uint32_t*)(g),                  \
    (__attribute__((address_space(3))) uint32_t*)(l), 16, 0, 0)

// ---------------------------------------------------------------------------
// Merged pre-pass: blocks [0, 8192) convert x fp32->f16;
// blocks [8192, 30208) dequant packed int4 -> f16 weights [OUT_F][IN_F].
// ---------------------------------------------------------------------------
#define XCONV_BLOCKS  (TOKENS * IN_F / 8 / 256)             // 8192
#define WDEQ_BLOCKS   (OUT_F * (IN_F / 2) / 4 / 256)        // 22016

__global__ __launch_bounds__(256)
void prepass_kernel(const float* __restrict__ x,
                    const int* __restrict__ wq,
                    const float* __restrict__ scale,
                    const float* __restrict__ zero,
                    __half* __restrict__ x16,
                    __half* __restrict__ w16)
{
  const int b = blockIdx.x;
  if (b < XCONV_BLOCKS) {
    const size_t i = ((size_t)b * 256 + threadIdx.x) * 8;
    const float4 a = *reinterpret_cast<const float4*>(x + i);
    const float4 c = *reinterpret_cast<const float4*>(x + i + 4);
    H8 r;
    r.h2[0] = __floats2half2_rn(a.x, a.y);
    r.h2[1] = __floats2half2_rn(a.z, a.w);
    r.h2[2] = __floats2half2_rn(c.x, c.y);
    r.h2[3] = __floats2half2_rn(c.z, c.w);
    *reinterpret_cast<uint4*>(x16 + i) = r.u4;
  } else {
    const size_t i = ((size_t)(b - XCONV_BLOCKS) * 256 + threadIdx.x) * 4;
    const int row = (int)(i >> 11);                 // 2048 int32 per row
    const float s  = scale[row];
    const float nb = -zero[row] * s;
    const int4 v = *reinterpret_cast<const int4*>(wq + i);
    H8 r;
    r.h2[0] = __floats2half2_rn(fmaf((float)(v.x & 15), s, nb),
                                fmaf((float)((v.x >> 4) & 15), s, nb));
    r.h2[1] = __floats2half2_rn(fmaf((float)(v.y & 15), s, nb),
                                fmaf((float)((v.y >> 4) & 15), s, nb));
    r.h2[2] = __floats2half2_rn(fmaf((float)(v.z & 15), s, nb),
                                fmaf((float)((v.z >> 4) & 15), s, nb));
    r.h2[3] = __floats2half2_rn(fmaf((float)(v.w & 15), s, nb),
                                fmaf((float)((v.w >> 4) & 15), s, nb));
    *reinterpret_cast<uint4*>(w16 + i * 2) = r.u4;
  }
}

// ---------------------------------------------------------------------------
// Main GEMM: 256x256 tile, BK=64, 8 waves (2Mx4N), 8-phase schedule with
// uniform per-phase vmcnt(6) (3 half-tiles in flight), XOR-swizzled LDS
// (both-sides via pre-swizzled gload src), setprio around MFMA clusters,
// bijective XCD blockIdx swizzle.
//
// LDS map (halves): buf b at b*32768. A rows 0..255 at rh*64 (A0=+0, A1=+8192),
// B at +16384 (B0) / +24576 (B1). Half-tile = 128 rows x 64 halves (16KB).
// Swizzle: within a 128B row, 16B slot s holds global slot s ^ (row&7).
//
// m-frag remap (enables 3-deep pipeline): frag i of wave-row wr sits at tile
// rows i*32 + wr*16 + [0,16). Phases 0/1 consume A0 only, 2/3 consume A1 only.
//
// Per iteration (K-tiles e=2i in buf0, o=2i+1 in buf1), 8 phases:
//  ph0 e: read all B(e)+A f01(e)[A0]; stage o.A0     -> buf1.A0
//  ph1 e: read A f23(e)[A0];          stage o.A1     -> buf1.A1
//  ph2 e: read A f45(e)[A1];          stage (e+2).B0 -> buf0.B0
//  ph3 e: read A f67(e)[A1];          stage (e+2).B1 -> buf0.B1
//  ph4 o: read all B(o)+A f01(o)[A0]; stage (e+2).A0 -> buf0.A0
//  ph5 o: read A f23(o)[A0];          stage (e+2).A1 -> buf0.A1
//  ph6 o: read A f45(o)[A1];          stage (o+2).B0 -> buf1.B0
//  ph7 o: read A f67(o)[A1];          stage (o+2).B1 -> buf1.B1
// Every phase ends with vmcnt(6): a stage lands <=3 phases after issue; all
// consume distances are >=3 phases (RAW ok), all stage issues are after the
// last read of the overwritten half-tile (WAR ok, barrier-ordered).
// ---------------------------------------------------------------------------

#define VMW6 asm volatile("s_waitcnt vmcnt(6)" ::: "memory")

#define STAGE_A(H, K0, LB)                                                    \
  do {                                                                        \
    GLOAD16(apst + (H) * 128 * IN_F + (K0), &smem[(LB) + c0 * 512]);          \
    GLOAD16(apst + (H) * 128 * IN_F + 8 * IN_F + (K0),                        \
            &smem[(LB) + c0 * 512 + 512]);                                    \
  } while (0)

#define STAGE_B(H, K0, LB)                                                    \
  do {                                                                        \
    GLOAD16(bpst + (H) * 128 * IN_F + (K0), &smem[(LB) + c0 * 512]);          \
    GLOAD16(bpst + (H) * 128 * IN_F + 8 * IN_F + (K0),                        \
            &smem[(LB) + c0 * 512 + 512]);                                    \
  } while (0)

#define PHASE(BUF, MB, READB, STAGE_STMT)                                     \
  do {                                                                        \
    const int _ar = (BUF) * 32768;                                            \
    const int _br = brootB + (BUF) * 32768;                                   \
    if (READB) {                                                              \
      _Pragma("unroll")                                                       \
      for (int _j = 0; _j < 4; ++_j) {                                        \
        const int _rh = bn_rh + _j * 16;                                      \
        bfr[_j][0] = *(const half8*)&smem[_br + _rh * 64 + acol0];            \
        bfr[_j][1] = *(const half8*)&smem[_br + _rh * 64 + acol1];            \
      }                                                                       \
    }                                                                         \
    half8 _af[2][2];                                                          \
    _Pragma("unroll")                                                         \
    for (int _ii = 0; _ii < 2; ++_ii) {                                       \
      const int _rh = am_rh + (MB) * 64 + _ii * 32;                           \
      _af[_ii][0] = *(const half8*)&smem[_ar + _rh * 64 + acol0];             \
      _af[_ii][1] = *(const half8*)&smem[_ar + _rh * 64 + acol1];             \
    }                                                                         \
    STAGE_STMT;                                                               \
    __builtin_amdgcn_sched_barrier(0);                                        \
    __builtin_amdgcn_s_barrier();                                             \
    asm volatile("s_waitcnt lgkmcnt(0)" ::: "memory");                        \
    __builtin_amdgcn_sched_barrier(0);                                        \
    __builtin_amdgcn_s_setprio(1);                                            \
    _Pragma("unroll")                                                         \
    for (int _ii = 0; _ii < 2; ++_ii)                                         \
      _Pragma("unroll")                                                       \
      for (int _j = 0; _j < 4; ++_j) {                                        \
        acc[(MB) * 2 + _ii][_j] = __builtin_amdgcn_mfma_f32_16x16x32_f16(     \
            _af[_ii][0], bfr[_j][0], acc[(MB) * 2 + _ii][_j], 0, 0, 0);       \
        acc[(MB) * 2 + _ii][_j] = __builtin_amdgcn_mfma_f32_16x16x32_f16(     \
            _af[_ii][1], bfr[_j][1], acc[(MB) * 2 + _ii][_j], 0, 0, 0);       \
      }                                                                       \
    __builtin_amdgcn_s_setprio(0);                                            \
    VMW6;                                                                     \
    __builtin_amdgcn_sched_barrier(0);                                        \
    __builtin_amdgcn_s_barrier();                                             \
  } while (0)

__global__ __launch_bounds__(512, 2)
void gemm256_kernel(const __half* __restrict__ A16,
                    const __half* __restrict__ W16,
                    float* __restrict__ out)
{
  __shared__ __half smem[65536];   // 128 KB: 2 bufs x (A 32KB + B 32KB)

  // bijective XCD swizzle: 688 = 8 * 86
  const int bid = blockIdx.x;
  const int wg  = (bid & 7) * 86 + (bid >> 3);
  const int mt  = wg / 43;
  const int nt  = wg - mt * 43;
  const int m0  = mt * 256;
  const int n0  = nt * 256;

  const int tid  = threadIdx.x;
  const int lane = tid & 63;
  const int wave = tid >> 6;          // 0..7
  const int wr   = wave >> 2;         // 0..1  (M)
  const int wc   = wave & 3;          // 0..3  (N)
  const int fm   = lane & 15;
  const int q4   = lane >> 4;

  // fragment-read constants (swizzled column offsets, halves)
  const int swz   = (fm & 7) << 3;
  const int acol0 = (q4 * 8) ^ swz;          // ks=0
  const int acol1 = (32 + q4 * 8) ^ swz;     // ks=1
  const int brootB = 16384 + (wc >> 1) * 8192;
  const int am_rh  = wr * 16 + fm;           // + mfrag*32 (interleaved remap)
  const int bn_rh  = (wc & 1) * 64 + fm;     // + nfrag*16

  // staging constants: chunk c covers half-tile rows [c*8, c*8+8)
  const int c0 = wave * 2;
  const int sr = lane >> 3;                         // sub-row 0..7 (= row&7)
  const int sc = ((lane & 7) ^ sr) * 8;             // pre-swizzled source slot
  const __half* apst = A16 + (size_t)(m0 + c0 * 8 + sr) * IN_F + sc;
  const __half* bpst = W16 + (size_t)(n0 + c0 * 8 + sr) * IN_F + sc;

  f32x4 acc[8][4];
#pragma unroll
  for (int i = 0; i < 8; ++i)
#pragma unroll
    for (int j = 0; j < 4; ++j)
      acc[i][j] = (f32x4){0.f, 0.f, 0.f, 0.f};

  half8 bfr[4][2];

  // ---- prologue: K0.B, K0.A -> buf0; K1.B -> buf1.B (K1.A staged in ph0/ph1)
  STAGE_B(0, 0, 16384);
  STAGE_B(1, 0, 16384 + 8192);
  STAGE_A(0, 0, 0);
  STAGE_A(1, 0, 8192);
  STAGE_B(0, 64, 32768 + 16384);
  STAGE_B(1, 64, 32768 + 16384 + 8192);
  asm volatile("s_waitcnt vmcnt(4)" ::: "memory");  // K0 fully landed
  __builtin_amdgcn_sched_barrier(0);
  __builtin_amdgcn_s_barrier();

#pragma unroll 1
  for (int it = 0; it < 32; ++it) {
    const int k_o = (it * 2 + 1) * 64;
    const int ke2 = ((it * 2 + 2) & 63) * 64;   // wrap keeps tail in-bounds
    const int ko2 = ((it * 2 + 3) & 63) * 64;
    // K-tile e from buf0
    PHASE(0, 0, 1, STAGE_A(0, k_o, 32768 + 0));
    PHASE(0, 1, 0, STAGE_A(1, k_o, 32768 + 8192));
    PHASE(0, 2, 0, STAGE_B(0, ke2, 16384));
    PHASE(0, 3, 0, STAGE_B(1, ke2, 16384 + 8192));
    // K-tile o from buf1
    PHASE(1, 0, 1, STAGE_A(0, ke2, 0));
    PHASE(1, 1, 0, STAGE_A(1, ke2, 8192));
    PHASE(1, 2, 0, STAGE_B(0, ko2, 32768 + 16384));
    PHASE(1, 3, 0, STAGE_B(1, ko2, 32768 + 16384 + 8192));
  }

  asm volatile("s_waitcnt vmcnt(0)" ::: "memory");  // drain tail stages

  // ---- epilogue: C/D layout col=lane&15 (n), row=(lane>>4)*4+reg (m)
  // frag i covers tile rows i*32 + wr*16 + [0,16)
  const int mbase = m0 + wr * 16 + q4 * 4;
  const int nbase = n0 + wc * 64 + fm;
#pragma unroll
  for (int i = 0; i < 8; ++i) {
#pragma unroll
    for (int j = 0; j < 4; ++j) {
#pragma unroll
      for (int r = 0; r < 4; ++r) {
        out[(size_t)(mbase + i * 32 + r) * OUT_F + (nbase + j * 16)] = acc[i][j][r];
      }
    }
  }
}

// ---------------------------------------------------------------------------
// Fallback (previous verified fused kernel) — used only if workspace too small.
// ---------------------------------------------------------------------------
#define BM  128
#define BN  128
#define BK  32
#define LDT 40
#define NKT (IN_F / BK)

__device__ inline __half2 dequant_byte(int v, __half2 s2, __half2 b2) {
  float lo = (float)(v & 15);
  float hi = (float)((v >> 4) & 15);
  return __hfma2(__floats2half2_rn(lo, hi), s2, b2);
}

__global__ __launch_bounds__(256, 2)
void int4_gemm_kernel(const float* __restrict__ x,
                      const int* __restrict__ wq,
                      const float* __restrict__ scale,
                      const float* __restrict__ zero,
                      float* __restrict__ out)
{
  __shared__ __half As[BM * LDT];
  __shared__ __half Bs[BN * LDT];

  const int tid  = threadIdx.x;
  const int n0   = blockIdx.x * BN;
  const int m0   = blockIdx.y * BM;
  const int lane = tid & 63;
  const int wave = tid >> 6;
  const int wm   = (wave >> 1) * 64;
  const int wn   = (wave & 1) * 64;

  const int rowb  = tid >> 1;
  const int bhalf = tid & 1;
  const float s = scale[n0 + rowb];
  const float z = zero[n0 + rowb];
  const __half2 s2 = __floats2half2_rn(s, s);
  const float   nb = -z * s;
  const __half2 b2 = __floats2half2_rn(nb, nb);
  const int* wp = wq + (size_t)(n0 + rowb) * (IN_F / 2) + bhalf * 8;

  const float* xp[4];
  int arow[4], ac4[4];
#pragma unroll
  for (int i = 0; i < 4; ++i) {
    int idx = tid + i * 256;
    arow[i] = idx >> 3;
    ac4[i]  = idx & 7;
    xp[i] = x + (size_t)(m0 + arow[i]) * IN_F + ac4[i] * 4;
  }

  f32x4 acc[4][4];
#pragma unroll
  for (int i = 0; i < 4; ++i)
#pragma unroll
    for (int j = 0; j < 4; ++j)
      acc[i][j] = (f32x4){0.f, 0.f, 0.f, 0.f};

  float4 apf[4];
  int4   bpf0, bpf1;
#pragma unroll
  for (int i = 0; i < 4; ++i) apf[i] = *(const float4*)(xp[i]);
  bpf0 = *(const int4*)(wp);
  bpf1 = *(const int4*)(wp + 4);

  for (int kt = 0; kt < NKT; ++kt) {
#pragma unroll
    for (int i = 0; i < 4; ++i) {
      H4 t;
      t.h2[0] = __floats2half2_rn(apf[i].x, apf[i].y);
      t.h2[1] = __floats2half2_rn(apf[i].z, apf[i].w);
      *reinterpret_cast<uint2*>(&As[arow[i] * LDT + ac4[i] * 4]) = t.u2;
    }
    {
      H8 r0, r1;
      r0.h2[0] = dequant_byte(bpf0.x, s2, b2);
      r0.h2[1] = dequant_byte(bpf0.y, s2, b2);
      r0.h2[2] = dequant_byte(bpf0.z, s2, b2);
      r0.h2[3] = dequant_byte(bpf0.w, s2, b2);
      r1.h2[0] = dequant_byte(bpf1.x, s2, b2);
      r1.h2[1] = dequant_byte(bpf1.y, s2, b2);
      r1.h2[2] = dequant_byte(bpf1.z, s2, b2);
      r1.h2[3] = dequant_byte(bpf1.w, s2, b2);
      *reinterpret_cast<uint4*>(&Bs[rowb * LDT + bhalf * 16 + 0]) = r0.u4;
      *reinterpret_cast<uint4*>(&Bs[rowb * LDT + bhalf * 16 + 8]) = r1.u4;
    }
    if (kt + 1 < NKT) {
#pragma unroll
      for (int i = 0; i < 4; ++i) apf[i] = *(const float4*)(xp[i] + (kt + 1) * BK);
      bpf0 = *(const int4*)(wp + (size_t)(kt + 1) * 16);
      bpf1 = *(const int4*)(wp + (size_t)(kt + 1) * 16 + 4);
    }
    __syncthreads();

    const int fm = lane & 15;
    const int q4 = lane >> 4;
    half8 af[4], bf[4];
#pragma unroll
    for (int i = 0; i < 4; ++i)
      af[i] = *reinterpret_cast<const half8*>(&As[(wm + i * 16 + fm) * LDT + q4 * 8]);
#pragma unroll
    for (int j = 0; j < 4; ++j)
      bf[j] = *reinterpret_cast<const half8*>(&Bs[(wn + j * 16 + fm) * LDT + q4 * 8]);
#pragma unroll
    for (int i = 0; i < 4; ++i)
#pragma unroll
      for (int j = 0; j < 4; ++j)
        acc[i][j] = __builtin_amdgcn_mfma_f32_16x16x32_f16(af[i], bf[j], acc[i][j], 0, 0, 0);
    __syncthreads();
  }

  const int col = lane & 15;
  const int r0q = (lane >> 4) * 4;
#pragma unroll
  for (int i = 0; i < 4; ++i) {
#pragma unroll
    for (int j = 0; j < 4; ++j) {
#pragma unroll
      for (int r = 0; r < 4; ++r) {
        const int m = m0 + wm + i * 16 + r0q + r;
        const int n = n0 + wn + j * 16 + col;
        out[(size_t)m * OUT_F + n] = acc[i][j][r];
      }
    }
  }
}

// ---------------------------------------------------------------------------
extern "C" void kernel_launch(void* const* d_in, const int* in_sizes, int n_in,
                              void* d_out, int out_size, void* d_ws, size_t ws_size,
                              hipStream_t stream) {
  const float* x     = (const float*)d_in[0];
  const int*   wq    = (const int*)d_in[1];
  const float* scale = (const float*)d_in[2];
  const float* zero  = (const float*)d_in[3];
  float* out = (float*)d_out;

  const size_t X16_BYTES = (size_t)TOKENS * IN_F * sizeof(__half);
  const size_t W16_BYTES = (size_t)OUT_F * IN_F * sizeof(__half);

  if (ws_size >= X16_BYTES + W16_BYTES) {
    __half* x16 = (__half*)d_ws;
    __half* w16 = (__half*)((char*)d_ws + X16_BYTES);
    prepass_kernel<<<XCONV_BLOCKS + WDEQ_BLOCKS, 256, 0, stream>>>(x, wq, scale, zero, x16, w16);
    gemm256_kernel<<<dim3((OUT_F / 256) * (TOKENS / 256)), 512, 0, stream>>>(x16, w16, out);
  } else {
    dim3 grid(OUT_F / BN, TOKENS / BM);
    int4_gemm_kernel<<<grid, 256, 0, stream>>>(x, wq, scale, zero, out);
  }
}